// Round 9
// baseline (120.569 us; speedup 1.0000x reference)
//
#include <hip/hip_runtime.h>
#include <math.h>

// Problem constants (fixed by the reference setup_inputs)
#define BB 4
#define TT 4096
#define SS 4096
#define EE 512
#define HH 64
#define NN 128          // Chebyshev nodes / polynomial degree
#define XR 6.0f         // interpolation half-range for x

// Workspace layout (floats), NO aliasing (~670 KB):
//  O8     : [B][8][N][H] ws + 0     (262144) slot-split atomic accumulator
//  Cmat   : [N][N]      ws + 262144 (16384)
//  qnA    : bf16 A-frags +278528    (4096 float-slots = 8192 bf16)
//  Wfrag  : bf16 B-frags +282624    (32768 float-slots = 65536 bf16)
//  Sm_part: [B][32][N]  +315392     (16384)
//
// Session lessons (measured):
//  R9 : cooperative grid.sync() ~50 us each on MI355X. Dispatch boundary ~5 us.
//  R10: kvattn 512-block split + LDS reduce cost +2.7 us. Keep 256 blocks.
//  R11: atomicAdd O fold (-1 kernel), Chebyshev Sm, fast_tanh: 134.4 -> 126.8.
//  R12: killed exposed-latency chains: 126.8 -> 117.7.
//  R13: kvattn 256 -> 512 thr: only -1.7 us (116.1).
//  R14: FAILED (+31.6): ticket tail w/ per-block __threadfence (L2 writeback
//       on 8 non-coherent XCD L2s ~30 us). Fences are the cost, not spin.
//  R15: revert + fp32 parity-split Clenshaw: 115.2.
//  R17: fence-free ticket: 123.0 (reverted). KEY: kvattn itself ~40-50 us,
//       MfmaUtil 1.8%/VALUBusy 4.6% -> ~95% stall, hiding under 43-us fills.
//  R18: atomic issue-order rotation: 114.1 (-1.1, ~noise). Order-contention
//       falsified; same-address depth (64 adds/address) untested. ALSO:
//       VGPR_Count=56 << ~100 needed -> compiler re-serialized p0 staging
//       (no min-waves hint => 8-wave VGPR target). Grid-limited occupancy is
//       really 2 waves/SIMD -> 256 VGPR budget available.
//  R19 (this round): (1) slot-split accumulator O8[B][8][N][H], slot =
//       blockIdx&7 -> same-address atomic depth 64 -> 8; final sums slots.
//       (2) __launch_bounds__(512,2) + p0 as 2x8-float4 rounds so the load
//       batch actually lives in registers. Readout: ~95-105 => atomics were
//       the stall; ~105-110 => codegen; >=112 => structural, declare floor.

typedef __attribute__((ext_vector_type(8))) __bf16 bf16x8;
typedef __attribute__((ext_vector_type(16))) float f32x16;

__device__ __forceinline__ unsigned short f2b(float f) {
  unsigned int u = __float_as_uint(f);
  return (unsigned short)((u + 0x7FFFu + ((u >> 16) & 1u)) >> 16);  // RNE
}

// tanh via HW exp+rcp: rel err ~1e-6, ~5 VALU ops vs ~25 for ocml tanhf.
__device__ __forceinline__ float fast_tanh(float v) {
  float e = __expf(fminf(60.0f, 2.0f * v));
  return (e - 1.0f) * __builtin_amdgcn_rcpf(e + 1.0f);
}

// ---------------------------------------------------------------------------
// Kernel A (prep+sm fused), 256 blocks:
//   blocks [0,64)   : Wfrag pack (kw||vw fp32 -> MFMA B-frag bf16)
//   blocks [64,128) : Cmat via int mod-512 + cosf; qnA A-frags; zero O8
//   blocks [128,256): Sm_part[b][chunk][m] via Chebyshev recurrence
// ---------------------------------------------------------------------------
__global__ __launch_bounds__(256) void prep_sm_kernel(
    const float* __restrict__ kw, const float* __restrict__ vw,
    const float* __restrict__ qw, const float* __restrict__ qb,
    const float* __restrict__ x, unsigned int* __restrict__ Wfrag,
    float* __restrict__ Cmat, unsigned short* __restrict__ qnA,
    float* __restrict__ Sm_part, float* __restrict__ Oz) {
  const int blk = blockIdx.x;
  if (blk < 64) {
    // Wfrag pack: ((nblk*32 + kstep)*64 + lane)*8 + j  (bf16 units)
    int idx = blk * 256 + threadIdx.x;  // [0, 16384)
    int jq = idx & 1;
    int l = (idx >> 1) & 63;
    int ks = (idx >> 7) & 31;
    int nb = idx >> 12;
    int n = nb * 32 + (l & 31);
    int k = ks * 16 + (l >> 5) * 8 + jq * 4;
    const float* row = (n < HH) ? (kw + n * EE + k) : (vw + (n - HH) * EE + k);
    float4 wv = *(const float4*)row;
    Wfrag[idx * 2] = (unsigned int)f2b(wv.x) | ((unsigned int)f2b(wv.y) << 16);
    Wfrag[idx * 2 + 1] =
        (unsigned int)f2b(wv.z) | ((unsigned int)f2b(wv.w) << 16);
  } else if (blk < 128) {
    int idx = (blk - 64) * 256 + threadIdx.x;  // [0, N*N)
    int m = idx >> 7;
    int j = idx & (NN - 1);
    // angle = pi*m*(2j+1)/256; exact reduction mod 2*pi (512 units of pi/256)
    int k = (m * (2 * j + 1)) & 511;
    if (k >= 256) k -= 512;
    Cmat[idx] = cosf((float)k * (float)(M_PI / 256.0));
    // zero the slot-split atomic accumulator: 16384 float4 = 256 KB
    ((float4*)Oz)[idx] = make_float4(0.f, 0.f, 0.f, 0.f);
    if (idx < 8192) {
      int h = idx & 63;
      int j2 = idx >> 6;  // [0,128)
      float th = (float)M_PI * ((float)j2 + 0.5f) * (1.0f / NN);
      float xj = XR * cosf(th);
      float val = tanhf(fmaf(xj, qw[h], qb[h]));
      // A-frag position for element (m=j2, k=h):
      int pos =
          (((j2 >> 5) * 4 + (h >> 4)) * 64 + (j2 & 31) + 32 * ((h >> 3) & 1)) *
              8 +
          (h & 7);
      qnA[pos] = f2b(val);
    }
  } else {
    // Sm via Chebyshev recurrence: cos(m*acos(xhat)) == T_m(xhat), exactly.
    __shared__ float Tm[128][NN + 1];  // 66048 B
    int blk2 = blk - 128;  // [0,128)
    int b = blk2 >> 5;
    int chunk = blk2 & 31;
    int tid = threadIdx.x;
    if (tid < 128) {
      float xh = x[b * TT + chunk * 128 + tid] * (1.0f / XR);
      xh = fminf(1.0f, fmaxf(-1.0f, xh));
      Tm[tid][0] = 1.0f;
      Tm[tid][1] = xh;
      float x2 = 2.0f * xh;
      float tm2 = 1.0f, tm1 = xh;
#pragma unroll 6
      for (int m = 2; m < NN; ++m) {
        float t = fmaf(x2, tm1, -tm2);
        Tm[tid][m] = t;
        tm2 = tm1;
        tm1 = t;
      }
    }
    __syncthreads();
    if (tid < 128) {
      float s = 0.f;
#pragma unroll 8
      for (int i = 0; i < 128; ++i) s += Tm[i][tid];
      Sm_part[(b * 32 + chunk) * NN + tid] = s;
    }
  }
}

// ---------------------------------------------------------------------------
// Kernel B (kv+attn, all-MFMA). One block (512 thr, 8 waves) per 64-row
// s-chunk of one batch. Wave w8 = (mh = w8>>2 [m/s-half], w = w8&3 [quarter]).
//  p0 : stage emb -> bf16 A-frags (2 rounds x 8 float4, register-resident)
//  p1 : kv MFMA;  p2: tanh epilogue -> ktB/vB;  p3: GEMM1 + exp + Z
//  p4 : pack e*invZ -> eA; GEMM2 -> atomicAdd into O8 slot (blockIdx&7)
// __launch_bounds__(512,2): grid-limited occupancy is 2 waves/SIMD -> allow
// up to 256 VGPR so the staging batch is register-resident (R18: cap 56).
// ---------------------------------------------------------------------------
__global__ __launch_bounds__(512, 2) void kvattn_kernel(
    const float* __restrict__ emb, const float* __restrict__ kb,
    const unsigned int* __restrict__ Wfrag, const unsigned short* __restrict__ qnA,
    const float* __restrict__ Cmat, const float* __restrict__ Sm_part,
    float* __restrict__ O) {
  __shared__ __align__(16) char smem[69120];
  unsigned short* A_lds = (unsigned short*)smem;         // 65536 B (p0/p1)
  unsigned short* ktB = (unsigned short*)smem;           // 8192 B  (p2+)
  unsigned short* vB = (unsigned short*)(smem + 8192);   // 8192 B  (p2+)
  unsigned short* eA = (unsigned short*)(smem + 16384);  // 16384 B (p4)
  float* zred = (float*)(smem + 65536);                  // 64*9 floats (2304 B)
  float* wql = (float*)(smem + 67840);                   // 128 (512 B)
  float* izl = (float*)(smem + 68352);                   // 64  (256 B)
  float* sml = (float*)(smem + 68608);                   // 128 (512 B)

  const int tid = threadIdx.x;
  const int row0 = blockIdx.x * 64;  // [0, B*S)
  const int bb = row0 >> 12;

  // ---- p0: stage A (64 rows x 512 k), fp32 -> bf16 frags ----
  // 2 rounds of 8 float4: 32-reg buffer, fully register-resident; each
  // round's 8 loads pipeline -> ~2 exposed latencies total.
  {
    int m = tid >> 3;  // 0..63 local row
    int c8 = tid & 7;
    const float* src = emb + (size_t)(row0 + m) * EE;
    unsigned short* dst = A_lds + (m >> 5) * 16384;
    int ml = m & 31;
#pragma unroll
    for (int half = 0; half < 2; ++half) {
      float4 buf[8];
#pragma unroll
      for (int it = 0; it < 8; ++it)
        buf[it] = *(const float4*)(src + (c8 + (half * 8 + it) * 8) * 4);
#pragma unroll
      for (int it = 0; it < 8; ++it) {
        int k = (c8 + (half * 8 + it) * 8) * 4;
        float4 v = buf[it];
        int kstep = k >> 4;
        int lane_f = ml + 32 * ((k >> 3) & 1);
        int j = k & 7;
        unsigned int lo =
            (unsigned int)f2b(v.x) | ((unsigned int)f2b(v.y) << 16);
        unsigned int hi =
            (unsigned int)f2b(v.z) | ((unsigned int)f2b(v.w) << 16);
        *(uint2*)&dst[(kstep * 64 + lane_f) * 8 + j] = make_uint2(lo, hi);
      }
    }
  }
  // p0b: Sm chunk-reduce (tid<128); fold DCT scale into sml
  if (tid < 128) {
    float s = 0.f;
#pragma unroll 8
    for (int c = 0; c < 32; ++c) s += Sm_part[(bb * 32 + c) * NN + tid];
    sml[tid] = s * ((tid == 0) ? (1.0f / NN) : (2.0f / NN));
  }
  __syncthreads();
  // p0c: wq[j] dot (tid<128), 4 independent accumulators.
  if (tid < 128) {
    float a0 = 0.f, a1 = 0.f, a2 = 0.f, a3 = 0.f;
#pragma unroll
    for (int m = 0; m < NN; m += 4) {
      a0 = fmaf(sml[m], Cmat[m * NN + tid], a0);
      a1 = fmaf(sml[m + 1], Cmat[(m + 1) * NN + tid], a1);
      a2 = fmaf(sml[m + 2], Cmat[(m + 2) * NN + tid], a2);
      a3 = fmaf(sml[m + 3], Cmat[(m + 3) * NN + tid], a3);
    }
    wql[tid] = (a0 + a1) + (a2 + a3);
  }

  // ---- p1: kv MFMA. wave (w = n-quarter, mh = m-half), one 16-reg acc ----
  const int w8 = tid >> 6;   // wave 0..7
  const int lane = tid & 63;
  const int w = w8 & 3;      // n-quarter (0,1=K cols; 2,3=V cols)
  const int mh = w8 >> 2;    // m-half (s rows mh*32..mh*32+31)
  f32x16 acc = {};
  const bf16x8* Bf = (const bf16x8*)Wfrag;
  const unsigned short* Ah = A_lds + mh * 16384;
#pragma unroll 4
  for (int kstep = 0; kstep < 32; ++kstep) {
    bf16x8 bfr = Bf[(w * 32 + kstep) * 64 + lane];
    bf16x8 a = *(const bf16x8*)&Ah[(kstep * 64 + lane) * 8];
    acc = __builtin_amdgcn_mfma_f32_32x32x16_bf16(a, bfr, acc, 0, 0, 0);
  }
  __syncthreads();  // A_lds dead; ktB/vB/eA alias it

  // ---- p2: epilogue -> bf16 B-frags in LDS ----
  // acc element: (s = mh*32 + sl(reg,lane), n = w*32 + (lane&31))
  {
    const int n = w * 32 + (lane & 31);
    if (w < 2) {  // K half: dest element (k=h=n, n_dim=s)
      float kbv = kb[n];
      const int ks_h = n >> 4;
      const int off_h = 32 * ((n >> 3) & 1);
      const int jj_h = n & 7;
#pragma unroll
      for (int reg = 0; reg < 16; ++reg) {
        int sl = (reg & 3) + 8 * (reg >> 2) + 4 * (lane >> 5);  // s in half
        ktB[((mh * 4 + ks_h) * 64 + sl + off_h) * 8 + jj_h] =
            f2b(fast_tanh(acc[reg] + kbv));
      }
    } else {  // V half: dest element (k=s, n_dim=h)
      int h = n - 64;
      const int nb_h = h >> 5;
      const int lm = h & 31;
#pragma unroll
      for (int reg = 0; reg < 16; ++reg) {
        int sl = (reg & 3) + 8 * (reg >> 2) + 4 * (lane >> 5);
        int s = mh * 32 + sl;
        vB[((nb_h * 4 + (s >> 4)) * 64 + lm + 32 * ((s >> 3) & 1)) * 8 +
           (s & 7)] = f2b(fast_tanh(acc[reg]));
      }
    }
  }
  __syncthreads();

  // ---- p3: GEMM1 l[j][s]: wave (jb = w, sh = mh) ----
  f32x16 l0 = {};
#pragma unroll
  for (int ks = 0; ks < 4; ++ks) {
    bf16x8 a = *(const bf16x8*)(qnA + ((w * 4 + ks) * 64 + lane) * 8);
    bf16x8 b0 = *(const bf16x8*)&ktB[((mh * 4 + ks) * 64 + lane) * 8];
    l0 = __builtin_amdgcn_mfma_f32_32x32x16_bf16(a, b0, l0, 0, 0, 0);
  }
  // exp + Z partials (j = w*32 + (reg&3)+8*(reg>>2)+4*(lane>>5), s fixed/lane)
  float e0[16];
  float zp = 0.f;
#pragma unroll
  for (int r = 0; r < 4; ++r) {
    float4 wq4 = *(const float4*)&wql[w * 32 + 8 * r + 4 * (lane >> 5)];
    float wa[4] = {wq4.x, wq4.y, wq4.z, wq4.w};
#pragma unroll
    for (int c = 0; c < 4; ++c) {
      int reg = 4 * r + c;
      e0[reg] = __expf(l0[reg] * 0.125f);
      zp = fmaf(wa[c], e0[reg], zp);
    }
  }
  zred[(mh * 32 + (lane & 31)) * 9 + w * 2 + (lane >> 5)] = zp;
  __syncthreads();
  if (tid < 64) {
    float sum = 0.f;
#pragma unroll
    for (int k = 0; k < 8; ++k) sum += zred[tid * 9 + k];
    izl[tid] = 1.0f / sum;
  }
  __syncthreads();

  // ---- p4: pack e*invZ -> eA (A-frag: m=j, k=s), then GEMM2 ----
  {
    const int s = mh * 32 + (lane & 31);
    const float iz = izl[s];
    const int q0 = w * 4 + (s >> 4);
    const int lof = 32 * ((s >> 3) & 1);
    const int idx = s & 7;
#pragma unroll
    for (int reg = 0; reg < 16; ++reg) {
      int jl = (reg & 3) + 8 * (reg >> 2) + 4 * (lane >> 5);  // j & 31
      eA[(q0 * 64 + jl + lof) * 8 + idx] = f2b(e0[reg] * iz);
    }
  }
  __syncthreads();
  // GEMM2 O[j][h]: wave (jb = w, hh = mh)
  f32x16 o0 = {};
#pragma unroll
  for (int ks = 0; ks < 4; ++ks) {
    bf16x8 a = *(const bf16x8*)&eA[((w * 4 + ks) * 64 + lane) * 8];
    bf16x8 b0 = *(const bf16x8*)&vB[((mh * 4 + ks) * 64 + lane) * 8];
    o0 = __builtin_amdgcn_mfma_f32_32x32x16_bf16(a, b0, o0, 0, 0, 0);
  }
  // R19: atomic reduction into slot (blockIdx&7) of O8[bb][8][N][H]:
  // same-address depth drops 64 -> 8; 8 concurrent line groups per batch.
  float* op = O + ((size_t)bb * 8 + (blockIdx.x & 7)) * (NN * HH);
  const int h0 = mh * 32 + (lane & 31);
  const int rot = blockIdx.x & 15;
#pragma unroll
  for (int rr = 0; rr < 16; ++rr) {
    int reg = (rr + rot) & 15;
    int j = w * 32 + (reg & 3) + 8 * (reg >> 2) + 4 * (lane >> 5);
    atomicAdd(&op[j * HH + h0], o0[reg]);
  }
}

// ---------------------------------------------------------------------------
// Kernel C (ynode+coef+final fused): 64 blocks x 256 threads.
//  head: sum the 8 O-slots (fp32), then ynode[b][j] = sum_h tanh(.)*pw[h]+pb
//  then: coef[b] via 2-acc fp64 DCT, then fp32 parity-split Clenshaw.
// ---------------------------------------------------------------------------
__global__ __launch_bounds__(256) void final_kernel(
    const float* __restrict__ x, const float* __restrict__ O,
    const float* __restrict__ pw, const float* __restrict__ pb,
    const float* __restrict__ Cmat, float* __restrict__ y) {
  const int idx = blockIdx.x * 256 + threadIdx.x;  // [0, B*T)
  const int b = idx >> 12;
  __shared__ float yl[NN];
  __shared__ float c[NN];
  // ---- ynode phase: thread = (j, half of h) ----
  {
    const int j = threadIdx.x >> 1;
    const int half = threadIdx.x & 1;
    const float4* pwv = (const float4*)(pw + half * 32);
    float4 ov[8];
#pragma unroll
    for (int q = 0; q < 8; ++q) ov[q] = make_float4(0.f, 0.f, 0.f, 0.f);
#pragma unroll
    for (int slot = 0; slot < 8; ++slot) {
      const float4* Os =
          (const float4*)(O + (((size_t)(b * 8 + slot) * NN + j) * HH) +
                          half * 32);
#pragma unroll
      for (int q = 0; q < 8; ++q) {
        float4 t = Os[q];
        ov[q].x += t.x; ov[q].y += t.y; ov[q].z += t.z; ov[q].w += t.w;
      }
    }
    float s = 0.f;
#pragma unroll
    for (int q = 0; q < 8; ++q) {
      float4 pv = pwv[q];
      s += fast_tanh(ov[q].x) * pv.x + fast_tanh(ov[q].y) * pv.y +
           fast_tanh(ov[q].z) * pv.z + fast_tanh(ov[q].w) * pv.w;
    }
    s += __shfl_xor(s, 1, 64);
    if (half == 0) yl[j] = s + pb[0];
  }
  __syncthreads();
  // ---- coef: fp64 DCT, 2 independent accumulators (pipelined) ----
  if (threadIdx.x < NN) {
    int m = threadIdx.x;
    double a0 = 0.0, a1 = 0.0;
#pragma unroll 4
    for (int j = 0; j < NN; j += 2) {
      a0 += (double)yl[j] * (double)Cmat[m * NN + j];
      a1 += (double)yl[j + 1] * (double)Cmat[m * NN + j + 1];
    }
    c[m] = (float)((a0 + a1) * ((m == 0 ? 1.0 : 2.0) / NN));
  }
  __syncthreads();
  // ---- fp32 parity-split Clenshaw: f = fe + x*fo, u = 2x^2-1 ----
  //   even: T_2k(x)=T_k(u);  odd: T_2k+1(x)=x*V_k(u), V0=1, V1=2u-1
  float xv = x[idx] * (1.0f / XR);
  xv = fminf(1.0f, fmaxf(-1.0f, xv));
  float uu = fmaf(2.0f * xv, xv, -1.0f);
  float tu = 2.0f * uu;
  float be1 = 0.f, be2 = 0.f, bo1 = 0.f, bo2 = 0.f;
  for (int m = 63; m >= 0; --m) {
    float ce = c[2 * m], co = c[2 * m + 1];
    float be = fmaf(tu, be1, ce - be2);
    float bo = fmaf(tu, bo1, co - bo2);
    be2 = be1; be1 = be;
    bo2 = bo1; bo1 = bo;
  }
  float fe = be1 - uu * be2;
  float fo = bo1 - bo2;
  y[idx] = fmaf(xv, fo, fe);
}

extern "C" void kernel_launch(void* const* d_in, const int* in_sizes, int n_in,
                              void* d_out, int out_size, void* d_ws,
                              size_t ws_size, hipStream_t stream) {
  const float* x = (const float*)d_in[0];
  const float* emb = (const float*)d_in[1];
  const float* kw = (const float*)d_in[2];
  const float* kb = (const float*)d_in[3];
  const float* qw = (const float*)d_in[4];
  const float* qb = (const float*)d_in[5];
  const float* vw = (const float*)d_in[6];
  const float* pw = (const float*)d_in[7];
  const float* pb = (const float*)d_in[8];

  float* ws = (float*)d_ws;
  float* O = ws;                                          // 262144 floats (8 slots)
  float* Cmat = ws + 262144;                              // 16384
  unsigned short* qnA = (unsigned short*)(Cmat + 16384);  // 4096 float-slots
  unsigned int* Wfrag = (unsigned int*)(Cmat + 16384 + 4096);  // 32768 slots
  float* Sm_part = (float*)(Wfrag + 32768);               // 16384
  float* y = (float*)d_out;

  prep_sm_kernel<<<256, 256, 0, stream>>>(kw, vw, qw, qb, x, Wfrag, Cmat, qnA,
                                          Sm_part, O);
  kvattn_kernel<<<BB * SS / 64, 512, 0, stream>>>(emb, kb, Wfrag, qnA, Cmat,
                                                  Sm_part, O);
  final_kernel<<<BB * TT / 256, 256, 0, stream>>>(x, O, pw, pb, Cmat, y);
}

// Round 10
// 113.687 us; speedup vs baseline: 1.0605x; 1.0605x over previous
//
#include <hip/hip_runtime.h>
#include <math.h>

// Problem constants (fixed by the reference setup_inputs)
#define BB 4
#define TT 4096
#define SS 4096
#define EE 512
#define HH 64
#define NN 128          // Chebyshev nodes / polynomial degree
#define XR 6.0f         // interpolation half-range for x

// Workspace layout (floats), NO aliasing (~410 KB):
//  O      : [B][N][H]   ws + 0      (32768)  atomic fp32 accumulator (zeroed by prep)
//  Cmat   : [N][N]      ws + 32768  (16384)
//  qnA    : bf16 A-frags +49152     (4096 float-slots = 8192 bf16)
//  Wfrag  : bf16 B-frags +53248     (32768 float-slots = 65536 bf16)
//  Sm_part: [B][32][N]  +86016     (16384)
//
// Session lessons (measured) — FINAL STATE (R20 = R18 revert, session best):
//  R9 : cooperative grid.sync() ~50 us each on MI355X. Dispatch boundary ~5 us.
//  R10: kvattn 512-block split + LDS reduce cost +2.7 us. Keep 256 blocks.
//  R11: atomicAdd O fold (-1 kernel), Chebyshev Sm, fast_tanh: 134.4 -> 126.8.
//  R12: killed exposed-latency chains (4-acc wq dot, batched staging, fp32
//       trig, grid 256): 126.8 -> 117.7. Per-block critical path is 1:1.
//  R13: kvattn 256 -> 512 thr (2 waves/SIMD): -1.7 us (116.1).
//  R14: FAILED (+31.6): ticket tail w/ per-block __threadfence -> L2
//       writeback on 8 non-coherent XCD L2s. Fences are the cost, not spin.
//  R15: revert + fp32 parity-split Clenshaw: 115.2.
//  R17: fence-free ticket: 123.0 (reverted). kvattn itself ~40-43 us at
//       ~95% stall (MfmaUtil 1.8%, VALUBusy 4.6%), hiding under 43-us fills.
//  R18: atomic issue-order rotation: 114.1 (session best).
//  R19: FAILED (+6.5): slot-split accumulator (atomic depth 64->8) AND
//       __launch_bounds__(512,2) register-resident staging both harmful.
//       Same-address atomic depth + VGPR starvation both falsified.
//  FLOOR: every structural axis measured: occupancy (R10/R13), fusion
//       (R14/R17), atomic order/depth (R18/R19), codegen (R19). kvattn's
//       ~40 us is structural for this decomposition; remaining window time
//       is harness re-poison fills (43-45 us @ 74-79% HBM peak) + ~10 us
//       boundaries. This kernel = practical floor.

typedef __attribute__((ext_vector_type(8))) __bf16 bf16x8;
typedef __attribute__((ext_vector_type(16))) float f32x16;

__device__ __forceinline__ unsigned short f2b(float f) {
  unsigned int u = __float_as_uint(f);
  return (unsigned short)((u + 0x7FFFu + ((u >> 16) & 1u)) >> 16);  // RNE
}

// tanh via HW exp+rcp: rel err ~1e-6, ~5 VALU ops vs ~25 for ocml tanhf.
__device__ __forceinline__ float fast_tanh(float v) {
  float e = __expf(fminf(60.0f, 2.0f * v));
  return (e - 1.0f) * __builtin_amdgcn_rcpf(e + 1.0f);
}

// ---------------------------------------------------------------------------
// Kernel A (prep+sm fused), 256 blocks:
//   blocks [0,64)   : Wfrag pack (kw||vw fp32 -> MFMA B-frag bf16)
//   blocks [64,128) : Cmat[m][j] = cos(m*pi*(j+.5)/N) via int mod-512 + cosf;
//                     also qnA A-frags + zero O (128 KB)
//   blocks [128,256): Sm_part[b][chunk][m] = sum_{128 t} T_m(xhat_t)
//                     via 1-FMA Chebyshev recurrence + LDS transpose-sum
// ---------------------------------------------------------------------------
__global__ __launch_bounds__(256) void prep_sm_kernel(
    const float* __restrict__ kw, const float* __restrict__ vw,
    const float* __restrict__ qw, const float* __restrict__ qb,
    const float* __restrict__ x, unsigned int* __restrict__ Wfrag,
    float* __restrict__ Cmat, unsigned short* __restrict__ qnA,
    float* __restrict__ Sm_part, float* __restrict__ Oz) {
  const int blk = blockIdx.x;
  if (blk < 64) {
    // Wfrag pack: ((nblk*32 + kstep)*64 + lane)*8 + j  (bf16 units)
    int idx = blk * 256 + threadIdx.x;  // [0, 16384)
    int jq = idx & 1;
    int l = (idx >> 1) & 63;
    int ks = (idx >> 7) & 31;
    int nb = idx >> 12;
    int n = nb * 32 + (l & 31);
    int k = ks * 16 + (l >> 5) * 8 + jq * 4;
    const float* row = (n < HH) ? (kw + n * EE + k) : (vw + (n - HH) * EE + k);
    float4 wv = *(const float4*)row;
    Wfrag[idx * 2] = (unsigned int)f2b(wv.x) | ((unsigned int)f2b(wv.y) << 16);
    Wfrag[idx * 2 + 1] =
        (unsigned int)f2b(wv.z) | ((unsigned int)f2b(wv.w) << 16);
  } else if (blk < 128) {
    int idx = (blk - 64) * 256 + threadIdx.x;  // [0, N*N)
    int m = idx >> 7;
    int j = idx & (NN - 1);
    // angle = pi*m*(2j+1)/256; exact reduction mod 2*pi (512 units of pi/256)
    int k = (m * (2 * j + 1)) & 511;
    if (k >= 256) k -= 512;
    Cmat[idx] = cosf((float)k * (float)(M_PI / 256.0));
    // zero the atomic O accumulator: 8192 float4 = 128 KB
    if (idx < 8192) ((float4*)Oz)[idx] = make_float4(0.f, 0.f, 0.f, 0.f);
    if (idx < 8192) {
      int h = idx & 63;
      int j2 = idx >> 6;  // [0,128)
      float th = (float)M_PI * ((float)j2 + 0.5f) * (1.0f / NN);
      float xj = XR * cosf(th);
      float val = tanhf(fmaf(xj, qw[h], qb[h]));
      // A-frag position for element (m=j2, k=h):
      int pos =
          (((j2 >> 5) * 4 + (h >> 4)) * 64 + (j2 & 31) + 32 * ((h >> 3) & 1)) *
              8 +
          (h & 7);
      qnA[pos] = f2b(val);
    }
  } else {
    // Sm via Chebyshev recurrence: cos(m*acos(xhat)) == T_m(xhat), exactly.
    // Tm[i][m], padded to 129 -> both row-write and column-read conflict-free.
    __shared__ float Tm[128][NN + 1];  // 66048 B
    int blk2 = blk - 128;  // [0,128)
    int b = blk2 >> 5;
    int chunk = blk2 & 31;
    int tid = threadIdx.x;
    if (tid < 128) {
      float xh = x[b * TT + chunk * 128 + tid] * (1.0f / XR);
      xh = fminf(1.0f, fmaxf(-1.0f, xh));
      Tm[tid][0] = 1.0f;
      Tm[tid][1] = xh;
      float x2 = 2.0f * xh;
      float tm2 = 1.0f, tm1 = xh;
#pragma unroll 6
      for (int m = 2; m < NN; ++m) {
        float t = fmaf(x2, tm1, -tm2);
        Tm[tid][m] = t;
        tm2 = tm1;
        tm1 = t;
      }
    }
    __syncthreads();
    if (tid < 128) {
      float s = 0.f;
#pragma unroll 8
      for (int i = 0; i < 128; ++i) s += Tm[i][tid];
      Sm_part[(b * 32 + chunk) * NN + tid] = s;
    }
  }
}

// ---------------------------------------------------------------------------
// Kernel B (kv+attn, all-MFMA). One block (512 thr, 8 waves) per 64-row
// s-chunk of one batch. Wave w8 = (mh = w8>>2 [m/s-half], w = w8&3 [quarter]).
//  p0 : stage emb -> bf16 A-frags (LDS, full 64 KB); tid<128 reduce Sm + wq
//  p1 : kv MFMA; wave (w,mh): acc = emb[mh-half] x W[quarter w] over K=512
//  p2 : epilogue tanh -> ktB (B-frag, k=h,n=s) / vB (B-frag, k=s,n=h), bf16
//  p3 : GEMM1 l[j][s]: wave (jb=w, sh=mh); e=exp(l/8); Z=sum_j wq_j*e
//  p4 : pack e*invZ -> eA (A-frag, m=j,k=s); GEMM2 wave (jb=w, hh=mh)
//       -> atomicAdd O fp32, issue order ROTATED by blockIdx&15 (R18)
// LDS: [0,65536) A_lds / frag buffers; [65536,69120) reduction tail.
// ---------------------------------------------------------------------------
__global__ __launch_bounds__(512) void kvattn_kernel(
    const float* __restrict__ emb, const float* __restrict__ kb,
    const unsigned int* __restrict__ Wfrag, const unsigned short* __restrict__ qnA,
    const float* __restrict__ Cmat, const float* __restrict__ Sm_part,
    float* __restrict__ O) {
  __shared__ __align__(16) char smem[69120];
  unsigned short* A_lds = (unsigned short*)smem;         // 65536 B (p0/p1)
  unsigned short* ktB = (unsigned short*)smem;           // 8192 B  (p2+)
  unsigned short* vB = (unsigned short*)(smem + 8192);   // 8192 B  (p2+)
  unsigned short* eA = (unsigned short*)(smem + 16384);  // 16384 B (p4)
  float* zred = (float*)(smem + 65536);                  // 64*9 floats (2304 B)
  float* wql = (float*)(smem + 67840);                   // 128 (512 B)
  float* izl = (float*)(smem + 68352);                   // 64  (256 B)
  float* sml = (float*)(smem + 68608);                   // 128 (512 B)

  const int tid = threadIdx.x;
  const int row0 = blockIdx.x * 64;  // [0, B*S)
  const int bb = row0 >> 12;

  // ---- p0: stage A (64 rows x 512 k), fp32 -> bf16 frags ----
  {
    int m = tid >> 3;  // 0..63 local row
    int c8 = tid & 7;
    const float* src = emb + (size_t)(row0 + m) * EE;
    unsigned short* dst = A_lds + (m >> 5) * 16384;
    int ml = m & 31;
    float4 buf[16];
#pragma unroll
    for (int it = 0; it < 16; ++it)
      buf[it] = *(const float4*)(src + (c8 + it * 8) * 4);
#pragma unroll
    for (int it = 0; it < 16; ++it) {
      int k = (c8 + it * 8) * 4;
      float4 v = buf[it];
      int kstep = k >> 4;
      int lane_f = ml + 32 * ((k >> 3) & 1);
      int j = k & 7;
      unsigned int lo = (unsigned int)f2b(v.x) | ((unsigned int)f2b(v.y) << 16);
      unsigned int hi = (unsigned int)f2b(v.z) | ((unsigned int)f2b(v.w) << 16);
      *(uint2*)&dst[(kstep * 64 + lane_f) * 8 + j] = make_uint2(lo, hi);
    }
  }
  // p0b: Sm chunk-reduce (tid<128); fold DCT scale into sml
  if (tid < 128) {
    float s = 0.f;
#pragma unroll 8
    for (int c = 0; c < 32; ++c) s += Sm_part[(bb * 32 + c) * NN + tid];
    sml[tid] = s * ((tid == 0) ? (1.0f / NN) : (2.0f / NN));
  }
  __syncthreads();
  // p0c: wq[j] dot (tid<128), 4 independent accumulators.
  if (tid < 128) {
    float a0 = 0.f, a1 = 0.f, a2 = 0.f, a3 = 0.f;
#pragma unroll
    for (int m = 0; m < NN; m += 4) {
      a0 = fmaf(sml[m], Cmat[m * NN + tid], a0);
      a1 = fmaf(sml[m + 1], Cmat[(m + 1) * NN + tid], a1);
      a2 = fmaf(sml[m + 2], Cmat[(m + 2) * NN + tid], a2);
      a3 = fmaf(sml[m + 3], Cmat[(m + 3) * NN + tid], a3);
    }
    wql[tid] = (a0 + a1) + (a2 + a3);
  }

  // ---- p1: kv MFMA. wave (w = n-quarter, mh = m-half), one 16-reg acc ----
  const int w8 = tid >> 6;   // wave 0..7
  const int lane = tid & 63;
  const int w = w8 & 3;      // n-quarter (0,1=K cols; 2,3=V cols)
  const int mh = w8 >> 2;    // m-half (s rows mh*32..mh*32+31)
  f32x16 acc = {};
  const bf16x8* Bf = (const bf16x8*)Wfrag;
  const unsigned short* Ah = A_lds + mh * 16384;
#pragma unroll 4
  for (int kstep = 0; kstep < 32; ++kstep) {
    bf16x8 bfr = Bf[(w * 32 + kstep) * 64 + lane];
    bf16x8 a = *(const bf16x8*)&Ah[(kstep * 64 + lane) * 8];
    acc = __builtin_amdgcn_mfma_f32_32x32x16_bf16(a, bfr, acc, 0, 0, 0);
  }
  __syncthreads();  // A_lds dead; ktB/vB/eA alias it

  // ---- p2: epilogue -> bf16 B-frags in LDS ----
  // acc element: (s = mh*32 + sl(reg,lane), n = w*32 + (lane&31))
  {
    const int n = w * 32 + (lane & 31);
    if (w < 2) {  // K half: dest element (k=h=n, n_dim=s)
      float kbv = kb[n];
      const int ks_h = n >> 4;
      const int off_h = 32 * ((n >> 3) & 1);
      const int jj_h = n & 7;
#pragma unroll
      for (int reg = 0; reg < 16; ++reg) {
        int sl = (reg & 3) + 8 * (reg >> 2) + 4 * (lane >> 5);  // s in half
        ktB[((mh * 4 + ks_h) * 64 + sl + off_h) * 8 + jj_h] =
            f2b(fast_tanh(acc[reg] + kbv));
      }
    } else {  // V half: dest element (k=s, n_dim=h)
      int h = n - 64;
      const int nb_h = h >> 5;
      const int lm = h & 31;
#pragma unroll
      for (int reg = 0; reg < 16; ++reg) {
        int sl = (reg & 3) + 8 * (reg >> 2) + 4 * (lane >> 5);
        int s = mh * 32 + sl;
        vB[((nb_h * 4 + (s >> 4)) * 64 + lm + 32 * ((s >> 3) & 1)) * 8 +
           (s & 7)] = f2b(fast_tanh(acc[reg]));
      }
    }
  }
  __syncthreads();

  // ---- p3: GEMM1 l[j][s]: wave (jb = w, sh = mh) ----
  f32x16 l0 = {};
#pragma unroll
  for (int ks = 0; ks < 4; ++ks) {
    bf16x8 a = *(const bf16x8*)(qnA + ((w * 4 + ks) * 64 + lane) * 8);
    bf16x8 b0 = *(const bf16x8*)&ktB[((mh * 4 + ks) * 64 + lane) * 8];
    l0 = __builtin_amdgcn_mfma_f32_32x32x16_bf16(a, b0, l0, 0, 0, 0);
  }
  // exp + Z partials (j = w*32 + (reg&3)+8*(reg>>2)+4*(lane>>5), s fixed/lane)
  float e0[16];
  float zp = 0.f;
#pragma unroll
  for (int r = 0; r < 4; ++r) {
    float4 wq4 = *(const float4*)&wql[w * 32 + 8 * r + 4 * (lane >> 5)];
    float wa[4] = {wq4.x, wq4.y, wq4.z, wq4.w};
#pragma unroll
    for (int c = 0; c < 4; ++c) {
      int reg = 4 * r + c;
      e0[reg] = __expf(l0[reg] * 0.125f);
      zp = fmaf(wa[c], e0[reg], zp);
    }
  }
  zred[(mh * 32 + (lane & 31)) * 9 + w * 2 + (lane >> 5)] = zp;
  __syncthreads();
  if (tid < 64) {
    float sum = 0.f;
#pragma unroll
    for (int k = 0; k < 8; ++k) sum += zred[tid * 9 + k];
    izl[tid] = 1.0f / sum;
  }
  __syncthreads();

  // ---- p4: pack e*invZ -> eA (A-frag: m=j, k=s), then GEMM2 ----
  {
    const int s = mh * 32 + (lane & 31);
    const float iz = izl[s];
    const int q0 = w * 4 + (s >> 4);
    const int lof = 32 * ((s >> 3) & 1);
    const int idx = s & 7;
#pragma unroll
    for (int reg = 0; reg < 16; ++reg) {
      int jl = (reg & 3) + 8 * (reg >> 2) + 4 * (lane >> 5);  // j & 31
      eA[(q0 * 64 + jl + lof) * 8 + idx] = f2b(e0[reg] * iz);
    }
  }
  __syncthreads();
  // GEMM2 O[j][h]: wave (jb = w, hh = mh)
  f32x16 o0 = {};
#pragma unroll
  for (int ks = 0; ks < 4; ++ks) {
    bf16x8 a = *(const bf16x8*)&eA[((w * 4 + ks) * 64 + lane) * 8];
    bf16x8 b0 = *(const bf16x8*)&vB[((mh * 4 + ks) * 64 + lane) * 8];
    o0 = __builtin_amdgcn_mfma_f32_32x32x16_bf16(a, b0, o0, 0, 0, 0);
  }
  // atomic s-chunk reduction into O[b][j][h] (device-scope fp32 add).
  // R18: rotate issue order by blockIdx&15 so concurrent blocks spread
  // across 16 line groups instead of lockstep over the same one.
  float* op = O + (size_t)bb * (NN * HH);
  const int h0 = mh * 32 + (lane & 31);
  const int rot = blockIdx.x & 15;
#pragma unroll
  for (int rr = 0; rr < 16; ++rr) {
    int reg = (rr + rot) & 15;
    int j = w * 32 + (reg & 3) + 8 * (reg >> 2) + 4 * (lane >> 5);
    atomicAdd(&op[j * HH + h0], o0[reg]);
  }
}

// ---------------------------------------------------------------------------
// Kernel C (ynode+coef+final fused): 64 blocks x 256 threads.
//  head: ynode[b][j] = sum_h tanh(O[b][j][h])*pw[h] + pb  (thread=(j,half),
//        32 KB L2 read per block, pair-combine via shfl_xor)
//  then: coef[b] via 2-acc fp64 DCT (redundant across blocks — trivial),
//        then fp32 parity-split Clenshaw per element (R14-validated).
// ---------------------------------------------------------------------------
__global__ __launch_bounds__(256) void final_kernel(
    const float* __restrict__ x, const float* __restrict__ O,
    const float* __restrict__ pw, const float* __restrict__ pb,
    const float* __restrict__ Cmat, float* __restrict__ y) {
  const int idx = blockIdx.x * 256 + threadIdx.x;  // [0, B*T)
  const int b = idx >> 12;
  __shared__ float yl[NN];
  __shared__ float c[NN];
  // ---- ynode phase ----
  {
    const int j = threadIdx.x >> 1;
    const int half = threadIdx.x & 1;
    const float4* Ov =
        (const float4*)(O + ((size_t)(b * NN + j) * HH + half * 32));
    const float4* pwv = (const float4*)(pw + half * 32);
    float s = 0.f;
#pragma unroll
    for (int q = 0; q < 8; ++q) {
      float4 ov = Ov[q];
      float4 pv = pwv[q];
      s += fast_tanh(ov.x) * pv.x + fast_tanh(ov.y) * pv.y +
           fast_tanh(ov.z) * pv.z + fast_tanh(ov.w) * pv.w;
    }
    s += __shfl_xor(s, 1, 64);
    if (half == 0) yl[j] = s + pb[0];
  }
  __syncthreads();
  // ---- coef: fp64 DCT, 2 independent accumulators (pipelined) ----
  if (threadIdx.x < NN) {
    int m = threadIdx.x;
    double a0 = 0.0, a1 = 0.0;
#pragma unroll 4
    for (int j = 0; j < NN; j += 2) {
      a0 += (double)yl[j] * (double)Cmat[m * NN + j];
      a1 += (double)yl[j + 1] * (double)Cmat[m * NN + j + 1];
    }
    c[m] = (float)((a0 + a1) * ((m == 0 ? 1.0 : 2.0) / NN));
  }
  __syncthreads();
  // ---- fp32 parity-split Clenshaw: f = fe + x*fo, u = 2x^2-1 ----
  //   even: T_2k(x)=T_k(u);  odd: T_2k+1(x)=x*V_k(u), V0=1, V1=2u-1
  float xv = x[idx] * (1.0f / XR);
  xv = fminf(1.0f, fmaxf(-1.0f, xv));
  float uu = fmaf(2.0f * xv, xv, -1.0f);
  float tu = 2.0f * uu;
  float be1 = 0.f, be2 = 0.f, bo1 = 0.f, bo2 = 0.f;
  for (int m = 63; m >= 0; --m) {
    float ce = c[2 * m], co = c[2 * m + 1];
    float be = fmaf(tu, be1, ce - be2);
    float bo = fmaf(tu, bo1, co - bo2);
    be2 = be1; be1 = be;
    bo2 = bo1; bo1 = bo;
  }
  float fe = be1 - uu * be2;
  float fo = bo1 - bo2;
  y[idx] = fmaf(xv, fo, fe);
}

extern "C" void kernel_launch(void* const* d_in, const int* in_sizes, int n_in,
                              void* d_out, int out_size, void* d_ws,
                              size_t ws_size, hipStream_t stream) {
  const float* x = (const float*)d_in[0];
  const float* emb = (const float*)d_in[1];
  const float* kw = (const float*)d_in[2];
  const float* kb = (const float*)d_in[3];
  const float* qw = (const float*)d_in[4];
  const float* qb = (const float*)d_in[5];
  const float* vw = (const float*)d_in[6];
  const float* pw = (const float*)d_in[7];
  const float* pb = (const float*)d_in[8];

  float* ws = (float*)d_ws;
  float* O = ws;                                          // 32768 floats
  float* Cmat = ws + 32768;                               // 16384
  unsigned short* qnA = (unsigned short*)(Cmat + 16384);  // 4096 float-slots
  unsigned int* Wfrag = (unsigned int*)(Cmat + 16384 + 4096);  // 32768 slots
  float* Sm_part = (float*)(Wfrag + 32768);               // 16384
  float* y = (float*)d_out;

  prep_sm_kernel<<<256, 256, 0, stream>>>(kw, vw, qw, qb, x, Wfrag, Cmat, qnA,
                                          Sm_part, O);
  kvattn_kernel<<<BB * SS / 64, 512, 0, stream>>>(emb, kb, Wfrag, qnA, Cmat,
                                                  Sm_part, O);
  final_kernel<<<BB * TT / 256, 256, 0, stream>>>(x, O, pw, pb, Cmat, y);
}